// Round 11
// baseline (439.133 us; speedup 1.0000x reference)
//
#include <hip/hip_runtime.h>
#include <stdint.h>

// Problem: N=2048, F=64, S=512, D=512
//   gi[n,f,g] = sum_s x[n,f,s] * W_ih[f,g,s]   (+ b_ih)
//   r=sig(gi_r+b_hr); z=sig(gi_z+b_hz); n=tanh(gi_n + r*b_hn); h=(1-z)*n
//
// R11: R10 (32x32x16, k-major conflict-free images) with BM 128->256:
//      4 waves (2 wm x 2 wd), each wave owns 128 rows x 96 cols ->
//      per seg: 4 A + 3 B ds_reads feed 12 MFMA (LDS bytes/FLOP -29%,
//      staging bytes/FLOP -30% vs R10's 64x96 waves). acc = 3x4 f32x16
//      (192 acc regs, ~242 total -> 2 waves/SIMD), LDS 56KB -> 2 blocks/CU.
//      Images/prepasses/epilogue/T1 unchanged.

#define NN 2048
#define FF 64
#define SS 512
#define DD 512
#define NKT 8

#define A_SLAB 16384   // 8 segs x 128 rows x 16B (per 128-row slab)
#define B_SLAB 24576   // 8 segs x 192 rows x 16B
#define XT_BYTES ((long)64 * 16 * 8 * A_SLAB)   // 134217728
#define WT_BYTES ((long)64 * 8 * 8 * B_SLAB)    // 100663296

typedef float f32x4 __attribute__((ext_vector_type(4)));
typedef float f32x16 __attribute__((ext_vector_type(16)));
typedef __bf16 bf16x8 __attribute__((ext_vector_type(8)));
typedef unsigned short ushort8 __attribute__((ext_vector_type(8)));
typedef unsigned int uint32x4 __attribute__((ext_vector_type(4)));

#define AS1 __attribute__((address_space(1)))
#define AS3 __attribute__((address_space(3)))

__device__ __forceinline__ void gload16(const void* gsrc, void* ldst) {
    __builtin_amdgcn_global_load_lds(
        (const AS1 unsigned int*)(uintptr_t)gsrc,
        (AS3 unsigned int*)(unsigned int)(uintptr_t)ldst,
        16, 0, 0);
}

__device__ __forceinline__ ushort8 cvt8(const f32x4 a, const f32x4 b) {
    ushort8 r;
    r[0] = __builtin_bit_cast(unsigned short, (__bf16)a[0]);
    r[1] = __builtin_bit_cast(unsigned short, (__bf16)a[1]);
    r[2] = __builtin_bit_cast(unsigned short, (__bf16)a[2]);
    r[3] = __builtin_bit_cast(unsigned short, (__bf16)a[3]);
    r[4] = __builtin_bit_cast(unsigned short, (__bf16)b[0]);
    r[5] = __builtin_bit_cast(unsigned short, (__bf16)b[1]);
    r[6] = __builtin_bit_cast(unsigned short, (__bf16)b[2]);
    r[7] = __builtin_bit_cast(unsigned short, (__bf16)b[3]);
    return r;
}

__device__ __forceinline__ float fast_sigmoid(float v) {
    return 1.0f / (1.0f + __expf(-v));
}
__device__ __forceinline__ float fast_tanh(float v) {
    return 1.0f - 2.0f / (__expf(2.0f * v) + 1.0f);
}

// ---------------- prepass: x -> bf16 K-MAJOR image tiles (unchanged) --------
extern "C" __global__ __launch_bounds__(256)
void prep_x(const float* __restrict__ x, ushort8* __restrict__ xT) {
    const int b  = blockIdx.x;            // 8192
    const int f  = b >> 7;
    const int mt = (b >> 3) & 15;         // 128-row slab
    const int kt = b & 7;
    const int t  = threadIdx.x;
    const long slab = (long)b * 1024;
#pragma unroll
    for (int p = 0; p < 4; ++p) {
        int q   = p * 256 + t;            // 0..1023
        int row = q >> 3;                 // 0..127
        int sp  = q & 7;                  // k-seg
        const f32x4* src = (const f32x4*)(x + ((long)(mt * 128 + row) * FF + f) * SS
                                          + kt * 64 + sp * 8);
        xT[slab + sp * 128 + row] = cvt8(src[0], src[1]);
    }
}

extern "C" __global__ __launch_bounds__(256)
void prep_w(const float* __restrict__ W, ushort8* __restrict__ wT) {
    const int b  = blockIdx.x;            // 4096
    const int f  = b >> 6;
    const int dt = (b >> 3) & 7;
    const int kt = b & 7;
    const int t  = threadIdx.x;
    const long slab = (long)b * 1536;
#pragma unroll
    for (int p = 0; p < 6; ++p) {
        int q    = p * 256 + t;           // 0..1535
        int rowg = q >> 3;                // 0..191 = gate*64 + rr
        int sp   = q & 7;
        int gate = rowg >> 6;
        int rr   = rowg & 63;
        const f32x4* src = (const f32x4*)(W + ((long)f * 1536 + gate * DD + dt * 64 + rr) * SS
                                          + kt * 64 + sp * 8);
        wT[slab + sp * 192 + rowg] = cvt8(src[0], src[1]);
    }
}

// ---------------- main GEMM + fused gates (256x192, 128x96/wave) ------------
extern "C" __global__ __launch_bounds__(256, 2)
void gru_gemm(const unsigned char* __restrict__ xT, const unsigned char* __restrict__ wT,
              const float* __restrict__ b_ih, const float* __restrict__ b_hh,
              float* __restrict__ out)
{
    // LDS: A slab0 16KB @0, A slab1 16KB @16384, B 24KB @32768 = 56KB
    __shared__ __align__(16) unsigned char lds[57344];

    const int t    = threadIdx.x;         // 0..255
    const int lane = t & 63;
    const int wid  = t >> 6;              // 0..3
    const int wm   = wid >> 1;            // 0..1 (128-row band -> A slab)
    const int wd   = wid & 1;             // 0..1 (32 d-cols, all 3 gates)
    const int crow = lane & 31;           // row/col within a 32-block
    const int hi   = lane >> 5;           // selects k-seg half

    // T1 XCD mapping: each XCD owns 8 consecutive f; d-tile innermost
    const int bid  = blockIdx.x;          // 0..4095
    const int xcd  = bid & 7;
    const int lid  = bid >> 3;            // 0..511
    const int work = xcd * 512 + lid;
    const int f    = work >> 6;           // 0..63
    const int rem  = work & 63;
    const int mt   = rem >> 3;            // 0..7 (256-row tiles)
    const int dt   = rem & 7;             // 0..7
    const int n0   = mt * 256;
    const int d0   = dt * 64;

    const unsigned char* aS0 = xT + (long)((f * 16 + mt * 2) * 8) * A_SLAB;
    const unsigned char* aS1 = xT + (long)((f * 16 + mt * 2 + 1) * 8) * A_SLAB;
    const unsigned char* bS  = wT + (long)((f * 8 + dt) * 8) * B_SLAB;
    const int ldsW = (t & 192) * 16;      // wid*1024 (wave-uniform)

    f32x16 acc[3][4];
#pragma unroll
    for (int g = 0; g < 3; ++g)
#pragma unroll
        for (int rb = 0; rb < 4; ++rb)
#pragma unroll
            for (int q = 0; q < 16; ++q)
                acc[g][rb][q] = 0.f;

    const int aBase = wm * 16384;         // this wave's A slab in LDS
    const int drow  = wd * 32 + crow;     // B row (d-col within gate)

    for (int kt = 0; kt < NKT; ++kt) {
        __syncthreads();   // prev iteration's ds_reads done
        // stage K-tile kt: identity 16B copies (k-major images)
#pragma unroll
        for (int p = 0; p < 4; ++p)
            gload16(aS0 + kt * A_SLAB + (p * 256 + t) * 16,
                    lds + p * 4096 + ldsW);
#pragma unroll
        for (int p = 0; p < 4; ++p)
            gload16(aS1 + kt * A_SLAB + (p * 256 + t) * 16,
                    lds + 16384 + p * 4096 + ldsW);
#pragma unroll
        for (int p = 0; p < 6; ++p)
            gload16(bS + kt * B_SLAB + (p * 256 + t) * 16,
                    lds + 32768 + p * 4096 + ldsW);
        __syncthreads();   // drains vmcnt -> tile visible

#pragma unroll
        for (int kk = 0; kk < 4; ++kk) {
            const int seg = 2 * kk + hi;       // 16B k-seg for this slice
            bf16x8 av[4], bv[3];
#pragma unroll
            for (int rb = 0; rb < 4; ++rb) {
                int off = aBase + seg * 2048 + (rb * 32 + crow) * 16;
                av[rb] = __builtin_bit_cast(bf16x8, *(const uint32x4*)(lds + off));
            }
#pragma unroll
            for (int g = 0; g < 3; ++g) {
                int off = 32768 + seg * 3072 + (g * 64 + drow) * 16;
                bv[g] = __builtin_bit_cast(bf16x8, *(const uint32x4*)(lds + off));
            }
            __builtin_amdgcn_s_setprio(1);
#pragma unroll
            for (int g = 0; g < 3; ++g)
#pragma unroll
                for (int rb = 0; rb < 4; ++rb)
                    acc[g][rb] = __builtin_amdgcn_mfma_f32_32x32x16_bf16(
                        av[rb], bv[g], acc[g][rb], 0, 0, 0);
            __builtin_amdgcn_s_setprio(0);
        }
    }

    // ---- fused gate epilogue: col = lane&31, row = (reg&3)+8*(reg>>2)+4*hi -
    const long bBase = (long)f * (3 * DD);
    const int d = d0 + wd * 32 + crow;
    const float bihr = b_ih[bBase + d];
    const float bihz = b_ih[bBase + DD + d];
    const float bihn = b_ih[bBase + 2 * DD + d];
    const float bhr  = b_hh[bBase + d];
    const float bhz  = b_hh[bBase + DD + d];
    const float bhn  = b_hh[bBase + 2 * DD + d];
#pragma unroll
    for (int rb = 0; rb < 4; ++rb) {
#pragma unroll
        for (int reg = 0; reg < 16; ++reg) {
            int row = wm * 128 + rb * 32 + (reg & 3) + 8 * (reg >> 2) + 4 * hi;
            float gr = acc[0][rb][reg] + bihr + bhr;
            float gz = acc[1][rb][reg] + bihz + bhz;
            float gy = acc[2][rb][reg] + bihn;
            float r  = fast_sigmoid(gr);
            float z  = fast_sigmoid(gz);
            float nv = fast_tanh(gy + r * bhn);
            long oi  = ((long)(n0 + row) * FF + f) * DD + d;
            out[oi]  = (1.0f - z) * nv;
        }
    }
}

// ---------------- fallback (R3 kernel) if ws too small ----------------
extern "C" __global__ __launch_bounds__(256, 3)
void gru_fused_fb(const float* __restrict__ x, const float* __restrict__ W,
                  const float* __restrict__ b_ih, const float* __restrict__ b_hh,
                  float* __restrict__ out)
{
    __shared__ __align__(16) unsigned char lds[28672];
    const int t     = threadIdx.x;
    const int lane  = t & 63;
    const int wid   = t >> 6;
    const int wm    = wid >> 1;
    const int wd    = wid & 1;
    const int lrow  = lane & 15;
    const int khalf = lane >> 4;
    const int bid  = blockIdx.x;
    const int xcd  = bid & 7;
    const int lid  = bid >> 3;
    const int work = xcd * 2048 + lid;
    const int f    = work >> 8;
    const int rem  = work & 255;
    const int n0   = (rem >> 4) * 128;
    const int d0   = (rem & 15) * 32;
    const int colSeg = t & 7;
    const int rBase  = t >> 3;
    const float* aPtr[4]; int aOff[4];
#pragma unroll
    for (int p = 0; p < 4; ++p) {
        int row = rBase + 32 * p;
        aPtr[p] = x + ((long)(n0 + row) * FF + f) * SS + colSeg * 8;
        aOff[p] = row * 128 + ((colSeg * 16) ^ ((row & 7) << 4));
    }
    const float* bPtr[3]; int bOff[3];
#pragma unroll
    for (int p = 0; p < 3; ++p) {
        int ra = rBase + 32 * p;
        int gate = ra >> 5, dr = ra & 31;
        bPtr[p] = W + ((long)f * 1536 + gate * DD + d0 + dr) * SS + colSeg * 8;
        bOff[p] = 16384 + gate * 4096 + dr * 128 + ((colSeg * 16) ^ ((dr & 7) << 4));
    }
    f32x4 acc[3][4];
#pragma unroll
    for (int g = 0; g < 3; ++g)
#pragma unroll
        for (int i = 0; i < 4; ++i) acc[g][i] = (f32x4){0.f, 0.f, 0.f, 0.f};
    f32x4 va[4][2], vb[3][2];
#pragma unroll
    for (int p = 0; p < 4; ++p) { const f32x4* g = (const f32x4*)aPtr[p]; va[p][0] = g[0]; va[p][1] = g[1]; }
#pragma unroll
    for (int p = 0; p < 3; ++p) { const f32x4* g = (const f32x4*)bPtr[p]; vb[p][0] = g[0]; vb[p][1] = g[1]; }
    for (int kt = 0; kt < 8; ++kt) {
        __syncthreads();
#pragma unroll
        for (int p = 0; p < 4; ++p) *(ushort8*)(lds + aOff[p]) = cvt8(va[p][0], va[p][1]);
#pragma unroll
        for (int p = 0; p < 3; ++p) *(ushort8*)(lds + bOff[p]) = cvt8(vb[p][0], vb[p][1]);
        __syncthreads();
        if (kt + 1 < 8) {
            const long koff = (long)(kt + 1) * 64;
#pragma unroll
            for (int p = 0; p < 4; ++p) { const f32x4* g = (const f32x4*)(aPtr[p] + koff); va[p][0] = g[0]; va[p][1] = g[1]; }
#pragma unroll
            for (int p = 0; p < 3; ++p) { const f32x4* g = (const f32x4*)(bPtr[p] + koff); vb[p][0] = g[0]; vb[p][1] = g[1]; }
        }
#pragma unroll
        for (int kb = 0; kb < 2; ++kb) {
            bf16x8 af[4];
#pragma unroll
            for (int i = 0; i < 4; ++i) {
                int row = wm * 64 + i * 16 + lrow;
                int off = row * 128 + ((kb * 64 + khalf * 16) ^ ((row & 7) << 4));
                af[i] = __builtin_bit_cast(bf16x8, *(const uint32x4*)(lds + off));
            }
            bf16x8 bfr[3];
#pragma unroll
            for (int g = 0; g < 3; ++g) {
                int dr = wd * 16 + lrow;
                int off = 16384 + g * 4096 + dr * 128 + ((kb * 64 + khalf * 16) ^ ((dr & 7) << 4));
                bfr[g] = __builtin_bit_cast(bf16x8, *(const uint32x4*)(lds + off));
            }
#pragma unroll
            for (int g = 0; g < 3; ++g)
#pragma unroll
                for (int i = 0; i < 4; ++i)
                    acc[g][i] = __builtin_amdgcn_mfma_f32_16x16x32_bf16(af[i], bfr[g], acc[g][i], 0, 0, 0);
        }
    }
    const long bBase = (long)f * 1536;
    {
        int d = d0 + wd * 16 + lrow;
        float bihr = b_ih[bBase + d], bihz = b_ih[bBase + DD + d], bihn = b_ih[bBase + 2 * DD + d];
        float bhr = b_hh[bBase + d], bhz = b_hh[bBase + DD + d], bhn = b_hh[bBase + 2 * DD + d];
#pragma unroll
        for (int i = 0; i < 4; ++i)
#pragma unroll
            for (int q = 0; q < 4; ++q) {
                int row = wm * 64 + i * 16 + khalf * 4 + q;
                float r  = fast_sigmoid(acc[0][i][q] + bihr + bhr);
                float z  = fast_sigmoid(acc[1][i][q] + bihz + bhz);
                float nv = fast_tanh(acc[2][i][q] + bihn + r * bhn);
                out[((long)(n0 + row) * FF + f) * DD + d] = (1.0f - z) * nv;
            }
    }
}

extern "C" void kernel_launch(void* const* d_in, const int* in_sizes, int n_in,
                              void* d_out, int out_size, void* d_ws, size_t ws_size,
                              hipStream_t stream) {
    const float* x   = (const float*)d_in[0];
    const float* W   = (const float*)d_in[1];
    const float* bih = (const float*)d_in[2];
    const float* bhh = (const float*)d_in[3];
    float* out       = (float*)d_out;

    if (ws_size >= (size_t)(XT_BYTES + WT_BYTES)) {
        unsigned char* xT = (unsigned char*)d_ws;
        unsigned char* wT = xT + XT_BYTES;
        prep_x<<<dim3(8192), dim3(256), 0, stream>>>(x, (ushort8*)xT);
        prep_w<<<dim3(4096), dim3(256), 0, stream>>>(W, (ushort8*)wT);
        gru_gemm<<<dim3(4096), dim3(256), 0, stream>>>(xT, wT, bih, bhh, out);
    } else {
        gru_fused_fb<<<dim3(16384), dim3(256), 0, stream>>>(x, W, bih, bhh, out);
    }
}

// Round 12
// 401.295 us; speedup vs baseline: 1.0943x; 1.0943x over previous
//
#include <hip/hip_runtime.h>
#include <stdint.h>

// Problem: N=2048, F=64, S=512, D=512
//   gi[n,f,g] = sum_s x[n,f,s] * W_ih[f,g,s]   (+ b_ih)
//   r=sig(gi_r+b_hr); z=sig(gi_z+b_hz); n=tanh(gi_n + r*b_hn); h=(1-z)*n
//
// R12: GEMM reverted to R10 exactly (best: 263us GEMM, MfmaUtil 37, 0
//      conflicts, 3+ blocks/CU). R11's 128x96/wave tile lost occupancy
//      (43->22.6%) and regressed -- K=512 is too short for deep tiles/pipes;
//      TLP wins. This round: merge the two prepasses into ONE dispatch
//      (12288 blocks) to cut a launch boundary + tail-wave gap.

#define NN 2048
#define FF 64
#define SS 512
#define DD 512
#define NKT 8

#define A_SLAB 16384   // 8 segs x 128 rows x 16B
#define B_SLAB 24576   // 8 segs x 192 rows x 16B
#define XT_BYTES ((long)64 * 16 * 8 * A_SLAB)   // 134217728
#define WT_BYTES ((long)64 * 8 * 8 * B_SLAB)    // 100663296

typedef float f32x4 __attribute__((ext_vector_type(4)));
typedef float f32x16 __attribute__((ext_vector_type(16)));
typedef __bf16 bf16x8 __attribute__((ext_vector_type(8)));
typedef unsigned short ushort8 __attribute__((ext_vector_type(8)));
typedef unsigned int uint32x4 __attribute__((ext_vector_type(4)));

#define AS1 __attribute__((address_space(1)))
#define AS3 __attribute__((address_space(3)))

__device__ __forceinline__ void gload16(const void* gsrc, void* ldst) {
    __builtin_amdgcn_global_load_lds(
        (const AS1 unsigned int*)(uintptr_t)gsrc,
        (AS3 unsigned int*)(unsigned int)(uintptr_t)ldst,
        16, 0, 0);
}

__device__ __forceinline__ ushort8 cvt8(const f32x4 a, const f32x4 b) {
    ushort8 r;
    r[0] = __builtin_bit_cast(unsigned short, (__bf16)a[0]);
    r[1] = __builtin_bit_cast(unsigned short, (__bf16)a[1]);
    r[2] = __builtin_bit_cast(unsigned short, (__bf16)a[2]);
    r[3] = __builtin_bit_cast(unsigned short, (__bf16)a[3]);
    r[4] = __builtin_bit_cast(unsigned short, (__bf16)b[0]);
    r[5] = __builtin_bit_cast(unsigned short, (__bf16)b[1]);
    r[6] = __builtin_bit_cast(unsigned short, (__bf16)b[2]);
    r[7] = __builtin_bit_cast(unsigned short, (__bf16)b[3]);
    return r;
}

__device__ __forceinline__ float fast_sigmoid(float v) {
    return 1.0f / (1.0f + __expf(-v));
}
__device__ __forceinline__ float fast_tanh(float v) {
    return 1.0f - 2.0f / (__expf(2.0f * v) + 1.0f);
}

// ---------------- merged prepass: x,W -> bf16 K-MAJOR image tiles -----------
// A image 16B unit = seg*128 + row; B image 16B unit = seg*192 + gate*64 + rr.
extern "C" __global__ __launch_bounds__(256)
void prep_xw(const float* __restrict__ x, const float* __restrict__ W,
             ushort8* __restrict__ xT, ushort8* __restrict__ wT) {
    const int t = threadIdx.x;
    int b = blockIdx.x;
    if (b < 8192) {                       // ---- x tile: (f, mt128, kt) ----
        const int f  = b >> 7;
        const int mt = (b >> 3) & 15;
        const int kt = b & 7;
        const long slab = (long)b * 1024;
#pragma unroll
        for (int p = 0; p < 4; ++p) {
            int q   = p * 256 + t;        // 0..1023
            int row = q >> 3;             // 0..127
            int sp  = q & 7;              // k-seg
            const f32x4* src = (const f32x4*)(x + ((long)(mt * 128 + row) * FF + f) * SS
                                              + kt * 64 + sp * 8);
            xT[slab + sp * 128 + row] = cvt8(src[0], src[1]);
        }
    } else {                              // ---- W tile: (f, dt, kt) ----
        b -= 8192;                        // 0..4095
        const int f  = b >> 6;
        const int dt = (b >> 3) & 7;
        const int kt = b & 7;
        const long slab = (long)b * 1536;
#pragma unroll
        for (int p = 0; p < 6; ++p) {
            int q    = p * 256 + t;       // 0..1535
            int rowg = q >> 3;            // 0..191 = gate*64 + rr
            int sp   = q & 7;
            int gate = rowg >> 6;
            int rr   = rowg & 63;
            const f32x4* src = (const f32x4*)(W + ((long)f * 1536 + gate * DD + dt * 64 + rr) * SS
                                              + kt * 64 + sp * 8);
            wT[slab + sp * 192 + rowg] = cvt8(src[0], src[1]);
        }
    }
}

// ---------------- main GEMM + fused gates (R10: 32x32x16, k-major LDS) ------
extern "C" __global__ __launch_bounds__(256, 3)
void gru_gemm(const unsigned char* __restrict__ xT, const unsigned char* __restrict__ wT,
              const float* __restrict__ b_ih, const float* __restrict__ b_hh,
              float* __restrict__ out)
{
    // LDS: A [8 seg][128 row]x16B (16KB) @0; B [8 seg][192 row]x16B (24KB) @16384
    __shared__ __align__(16) unsigned char lds[40960];

    const int t    = threadIdx.x;         // 0..255
    const int lane = t & 63;
    const int wid  = t >> 6;              // 0..3
    const int wm   = wid >> 1;            // 0..1 (64-row band)
    const int wd   = wid & 1;             // 0..1 (32 d-cols, all 3 gates)
    const int crow = lane & 31;           // row/col within a 32-block
    const int hi   = lane >> 5;           // selects k-seg half

    // T1 XCD mapping: each XCD owns 8 consecutive f; d-tile innermost
    const int bid  = blockIdx.x;          // 0..8191
    const int xcd  = bid & 7;
    const int lid  = bid >> 3;
    const int work = xcd * 1024 + lid;
    const int f    = work >> 7;           // 0..63
    const int rem  = work & 127;
    const int mt   = rem >> 3;            // 0..15 (128-row tiles)
    const int dt   = rem & 7;             // 0..7
    const int n0   = mt * 128;
    const int d0   = dt * 64;

    const unsigned char* aSlab = xT + (long)((f * 16 + mt) * 8) * A_SLAB;
    const unsigned char* bSlab = wT + (long)((f * 8 + dt) * 8) * B_SLAB;
    const int ldsW = (t & 192) * 16;      // wid*1024 (wave-uniform)

    f32x16 acc[3][2];
#pragma unroll
    for (int g = 0; g < 3; ++g)
#pragma unroll
        for (int rb = 0; rb < 2; ++rb)
#pragma unroll
            for (int q = 0; q < 16; ++q)
                acc[g][rb][q] = 0.f;

    const int arow0 = wm * 64 + crow;          // rb=0 row
    const int arow1 = arow0 + 32;              // rb=1 row
    const int drow  = wd * 32 + crow;          // B row (d-col within gate)

    for (int kt = 0; kt < NKT; ++kt) {
        __syncthreads();   // prev iteration's ds_reads done
        // stage K-tile kt: identity 16B copies (k-major images)
#pragma unroll
        for (int p = 0; p < 4; ++p)
            gload16(aSlab + kt * A_SLAB + (p * 256 + t) * 16,
                    lds + p * 4096 + ldsW);
#pragma unroll
        for (int p = 0; p < 6; ++p)
            gload16(bSlab + kt * B_SLAB + (p * 256 + t) * 16,
                    lds + 16384 + p * 4096 + ldsW);
        __syncthreads();   // drains vmcnt -> tile visible

#pragma unroll
        for (int kk = 0; kk < 4; ++kk) {
            const int seg = 2 * kk + hi;       // 16B k-seg for this slice
            bf16x8 av[2], bv[3];
            {
                int off = seg * 2048 + arow0 * 16;   // contiguous across lanes
                av[0] = __builtin_bit_cast(bf16x8, *(const uint32x4*)(lds + off));
                off = seg * 2048 + arow1 * 16;
                av[1] = __builtin_bit_cast(bf16x8, *(const uint32x4*)(lds + off));
            }
#pragma unroll
            for (int g = 0; g < 3; ++g) {
                int off = 16384 + seg * 3072 + (g * 64 + drow) * 16;
                bv[g] = __builtin_bit_cast(bf16x8, *(const uint32x4*)(lds + off));
            }
            __builtin_amdgcn_s_setprio(1);
#pragma unroll
            for (int g = 0; g < 3; ++g)
#pragma unroll
                for (int rb = 0; rb < 2; ++rb)
                    acc[g][rb] = __builtin_amdgcn_mfma_f32_32x32x16_bf16(
                        av[rb], bv[g], acc[g][rb], 0, 0, 0);
            __builtin_amdgcn_s_setprio(0);
        }
    }

    // ---- fused gate epilogue: col = lane&31, row = (reg&3)+8*(reg>>2)+4*hi -
    const long bBase = (long)f * (3 * DD);
    const int d = d0 + wd * 32 + crow;
    const float bihr = b_ih[bBase + d];
    const float bihz = b_ih[bBase + DD + d];
    const float bihn = b_ih[bBase + 2 * DD + d];
    const float bhr  = b_hh[bBase + d];
    const float bhz  = b_hh[bBase + DD + d];
    const float bhn  = b_hh[bBase + 2 * DD + d];
#pragma unroll
    for (int rb = 0; rb < 2; ++rb) {
#pragma unroll
        for (int reg = 0; reg < 16; ++reg) {
            int row = wm * 64 + rb * 32 + (reg & 3) + 8 * (reg >> 2) + 4 * hi;
            float gr = acc[0][rb][reg] + bihr + bhr;
            float gz = acc[1][rb][reg] + bihz + bhz;
            float gy = acc[2][rb][reg] + bihn;
            float r  = fast_sigmoid(gr);
            float z  = fast_sigmoid(gz);
            float nv = fast_tanh(gy + r * bhn);
            long oi  = ((long)(n0 + row) * FF + f) * DD + d;
            out[oi]  = (1.0f - z) * nv;
        }
    }
}

// ---------------- fallback (R3 kernel) if ws too small ----------------
extern "C" __global__ __launch_bounds__(256, 3)
void gru_fused_fb(const float* __restrict__ x, const float* __restrict__ W,
                  const float* __restrict__ b_ih, const float* __restrict__ b_hh,
                  float* __restrict__ out)
{
    __shared__ __align__(16) unsigned char lds[28672];
    const int t     = threadIdx.x;
    const int lane  = t & 63;
    const int wid   = t >> 6;
    const int wm    = wid >> 1;
    const int wd    = wid & 1;
    const int lrow  = lane & 15;
    const int khalf = lane >> 4;
    const int bid  = blockIdx.x;
    const int xcd  = bid & 7;
    const int lid  = bid >> 3;
    const int work = xcd * 2048 + lid;
    const int f    = work >> 8;
    const int rem  = work & 255;
    const int n0   = (rem >> 4) * 128;
    const int d0   = (rem & 15) * 32;
    const int colSeg = t & 7;
    const int rBase  = t >> 3;
    const float* aPtr[4]; int aOff[4];
#pragma unroll
    for (int p = 0; p < 4; ++p) {
        int row = rBase + 32 * p;
        aPtr[p] = x + ((long)(n0 + row) * FF + f) * SS + colSeg * 8;
        aOff[p] = row * 128 + ((colSeg * 16) ^ ((row & 7) << 4));
    }
    const float* bPtr[3]; int bOff[3];
#pragma unroll
    for (int p = 0; p < 3; ++p) {
        int ra = rBase + 32 * p;
        int gate = ra >> 5, dr = ra & 31;
        bPtr[p] = W + ((long)f * 1536 + gate * DD + d0 + dr) * SS + colSeg * 8;
        bOff[p] = 16384 + gate * 4096 + dr * 128 + ((colSeg * 16) ^ ((dr & 7) << 4));
    }
    f32x4 acc[3][4];
#pragma unroll
    for (int g = 0; g < 3; ++g)
#pragma unroll
        for (int i = 0; i < 4; ++i) acc[g][i] = (f32x4){0.f, 0.f, 0.f, 0.f};
    f32x4 va[4][2], vb[3][2];
#pragma unroll
    for (int p = 0; p < 4; ++p) { const f32x4* g = (const f32x4*)aPtr[p]; va[p][0] = g[0]; va[p][1] = g[1]; }
#pragma unroll
    for (int p = 0; p < 3; ++p) { const f32x4* g = (const f32x4*)bPtr[p]; vb[p][0] = g[0]; vb[p][1] = g[1]; }
    for (int kt = 0; kt < 8; ++kt) {
        __syncthreads();
#pragma unroll
        for (int p = 0; p < 4; ++p) *(ushort8*)(lds + aOff[p]) = cvt8(va[p][0], va[p][1]);
#pragma unroll
        for (int p = 0; p < 3; ++p) *(ushort8*)(lds + bOff[p]) = cvt8(vb[p][0], vb[p][1]);
        __syncthreads();
        if (kt + 1 < 8) {
            const long koff = (long)(kt + 1) * 64;
#pragma unroll
            for (int p = 0; p < 4; ++p) { const f32x4* g = (const f32x4*)(aPtr[p] + koff); va[p][0] = g[0]; va[p][1] = g[1]; }
#pragma unroll
            for (int p = 0; p < 3; ++p) { const f32x4* g = (const f32x4*)(bPtr[p] + koff); vb[p][0] = g[0]; vb[p][1] = g[1]; }
        }
#pragma unroll
        for (int kb = 0; kb < 2; ++kb) {
            bf16x8 af[4];
#pragma unroll
            for (int i = 0; i < 4; ++i) {
                int row = wm * 64 + i * 16 + lrow;
                int off = row * 128 + ((kb * 64 + khalf * 16) ^ ((row & 7) << 4));
                af[i] = __builtin_bit_cast(bf16x8, *(const uint32x4*)(lds + off));
            }
            bf16x8 bfr[3];
#pragma unroll
            for (int g = 0; g < 3; ++g) {
                int dr = wd * 16 + lrow;
                int off = 16384 + g * 4096 + dr * 128 + ((kb * 64 + khalf * 16) ^ ((dr & 7) << 4));
                bfr[g] = __builtin_bit_cast(bf16x8, *(const uint32x4*)(lds + off));
            }
#pragma unroll
            for (int g = 0; g < 3; ++g)
#pragma unroll
                for (int i = 0; i < 4; ++i)
                    acc[g][i] = __builtin_amdgcn_mfma_f32_16x16x32_bf16(af[i], bfr[g], acc[g][i], 0, 0, 0);
        }
    }
    const long bBase = (long)f * 1536;
    {
        int d = d0 + wd * 16 + lrow;
        float bihr = b_ih[bBase + d], bihz = b_ih[bBase + DD + d], bihn = b_ih[bBase + 2 * DD + d];
        float bhr = b_hh[bBase + d], bhz = b_hh[bBase + DD + d], bhn = b_hh[bBase + 2 * DD + d];
#pragma unroll
    for (int i = 0; i < 4; ++i)
#pragma unroll
            for (int q = 0; q < 4; ++q) {
                int row = wm * 64 + i * 16 + khalf * 4 + q;
                float r  = fast_sigmoid(acc[0][i][q] + bihr + bhr);
                float z  = fast_sigmoid(acc[1][i][q] + bihz + bhz);
                float nv = fast_tanh(acc[2][i][q] + bihn + r * bhn);
                out[((long)(n0 + row) * FF + f) * DD + d] = (1.0f - z) * nv;
            }
    }
}

extern "C" void kernel_launch(void* const* d_in, const int* in_sizes, int n_in,
                              void* d_out, int out_size, void* d_ws, size_t ws_size,
                              hipStream_t stream) {
    const float* x   = (const float*)d_in[0];
    const float* W   = (const float*)d_in[1];
    const float* bih = (const float*)d_in[2];
    const float* bhh = (const float*)d_in[3];
    float* out       = (float*)d_out;

    if (ws_size >= (size_t)(XT_BYTES + WT_BYTES)) {
        unsigned char* xT = (unsigned char*)d_ws;
        unsigned char* wT = xT + XT_BYTES;
        prep_xw<<<dim3(12288), dim3(256), 0, stream>>>(x, W, (ushort8*)xT, (ushort8*)wT);
        gru_gemm<<<dim3(8192), dim3(256), 0, stream>>>(xT, wT, bih, bhh, out);
    } else {
        gru_fused_fb<<<dim3(16384), dim3(256), 0, stream>>>(x, W, bih, bhh, out);
    }
}

// Round 13
// 398.318 us; speedup vs baseline: 1.1025x; 1.0075x over previous
//
#include <hip/hip_runtime.h>
#include <stdint.h>

// Problem: N=2048, F=64, S=512, D=512
//   gi[n,f,g] = sum_s x[n,f,s] * W_ih[f,g,s]   (+ b_ih)
//   r=sig(gi_r+b_hr); z=sig(gi_z+b_hz); n=tanh(gi_n + r*b_hn); h=(1-z)*n
//
// R13: GEMM identical to R10/R12 (263us, MfmaUtil 37, 0 conflicts, 3 bl/CU).
//      Prepass now does an in-LDS transpose so IMAGE WRITES are linear
//      (1KB contiguous per wave, was 8x128B scattered runs):
//      phase1 coalesced reads -> swizzled LDS (idx=row*8+(sp^(row&7)),
//      2-way banks both phases), barrier, phase2 linear global writes.

#define NN 2048
#define FF 64
#define SS 512
#define DD 512
#define NKT 8

#define A_SLAB 16384   // 8 segs x 128 rows x 16B
#define B_SLAB 24576   // 8 segs x 192 rows x 16B
#define XT_BYTES ((long)64 * 16 * 8 * A_SLAB)   // 134217728
#define WT_BYTES ((long)64 * 8 * 8 * B_SLAB)    // 100663296

typedef float f32x4 __attribute__((ext_vector_type(4)));
typedef float f32x16 __attribute__((ext_vector_type(16)));
typedef __bf16 bf16x8 __attribute__((ext_vector_type(8)));
typedef unsigned short ushort8 __attribute__((ext_vector_type(8)));
typedef unsigned int uint32x4 __attribute__((ext_vector_type(4)));

#define AS1 __attribute__((address_space(1)))
#define AS3 __attribute__((address_space(3)))

__device__ __forceinline__ void gload16(const void* gsrc, void* ldst) {
    __builtin_amdgcn_global_load_lds(
        (const AS1 unsigned int*)(uintptr_t)gsrc,
        (AS3 unsigned int*)(unsigned int)(uintptr_t)ldst,
        16, 0, 0);
}

__device__ __forceinline__ ushort8 cvt8(const f32x4 a, const f32x4 b) {
    ushort8 r;
    r[0] = __builtin_bit_cast(unsigned short, (__bf16)a[0]);
    r[1] = __builtin_bit_cast(unsigned short, (__bf16)a[1]);
    r[2] = __builtin_bit_cast(unsigned short, (__bf16)a[2]);
    r[3] = __builtin_bit_cast(unsigned short, (__bf16)a[3]);
    r[4] = __builtin_bit_cast(unsigned short, (__bf16)b[0]);
    r[5] = __builtin_bit_cast(unsigned short, (__bf16)b[1]);
    r[6] = __builtin_bit_cast(unsigned short, (__bf16)b[2]);
    r[7] = __builtin_bit_cast(unsigned short, (__bf16)b[3]);
    return r;
}

__device__ __forceinline__ float fast_sigmoid(float v) {
    return 1.0f / (1.0f + __expf(-v));
}
__device__ __forceinline__ float fast_tanh(float v) {
    return 1.0f - 2.0f / (__expf(2.0f * v) + 1.0f);
}

// ---------------- merged prepass with in-LDS transpose ----------------------
// A image 16B unit = seg*128 + row; B image 16B unit = seg*192 + gate*64 + rr.
extern "C" __global__ __launch_bounds__(256)
void prep_xw(const float* __restrict__ x, const float* __restrict__ W,
             ushort8* __restrict__ xT, ushort8* __restrict__ wT) {
    __shared__ ushort8 sbuf[1536];        // 24KB (x uses first 16KB)
    const int t = threadIdx.x;
    int b = blockIdx.x;
    if (b < 8192) {                       // ---- x tile: (f, mt128, kt) ----
        const int f  = b >> 7;
        const int mt = (b >> 3) & 15;
        const int kt = b & 7;
        const long slab = (long)b * 1024;
        // phase 1: coalesced 256B-run reads -> swizzled LDS
#pragma unroll
        for (int p = 0; p < 4; ++p) {
            int q   = p * 256 + t;        // 0..1023
            int row = q >> 3;             // 0..127
            int sp  = q & 7;              // k-seg
            const f32x4* src = (const f32x4*)(x + ((long)(mt * 128 + row) * FF + f) * SS
                                              + kt * 64 + sp * 8);
            sbuf[row * 8 + (sp ^ (row & 7))] = cvt8(src[0], src[1]);
        }
        __syncthreads();
        // phase 2: LDS -> LINEAR global writes (1KB/wave contiguous)
#pragma unroll
        for (int p = 0; p < 4; ++p) {
            int u   = p * 256 + t;        // image unit = sp*128+row
            int sp  = u >> 7;
            int row = u & 127;
            xT[slab + u] = sbuf[row * 8 + (sp ^ (row & 7))];
        }
    } else {                              // ---- W tile: (f, dt, kt) ----
        b -= 8192;                        // 0..4095
        const int f  = b >> 6;
        const int dt = (b >> 3) & 7;
        const int kt = b & 7;
        const long slab = (long)b * 1536;
#pragma unroll
        for (int p = 0; p < 6; ++p) {
            int q    = p * 256 + t;       // 0..1535
            int rowg = q >> 3;            // 0..191 = gate*64 + rr
            int sp   = q & 7;
            const f32x4* src = (const f32x4*)(W + ((long)f * 1536 + (rowg >> 6) * DD
                                              + dt * 64 + (rowg & 63)) * SS
                                              + kt * 64 + sp * 8);
            sbuf[rowg * 8 + (sp ^ (rowg & 7))] = cvt8(src[0], src[1]);
        }
        __syncthreads();
#pragma unroll
        for (int p = 0; p < 6; ++p) {
            int u    = p * 256 + t;       // image unit = sp*192+rowg
            int sp   = u / 192;
            int rowg = u - sp * 192;
            wT[slab + u] = sbuf[rowg * 8 + (sp ^ (rowg & 7))];
        }
    }
}

// ---------------- main GEMM + fused gates (R10: 32x32x16, k-major LDS) ------
extern "C" __global__ __launch_bounds__(256, 3)
void gru_gemm(const unsigned char* __restrict__ xT, const unsigned char* __restrict__ wT,
              const float* __restrict__ b_ih, const float* __restrict__ b_hh,
              float* __restrict__ out)
{
    // LDS: A [8 seg][128 row]x16B (16KB) @0; B [8 seg][192 row]x16B (24KB) @16384
    __shared__ __align__(16) unsigned char lds[40960];

    const int t    = threadIdx.x;         // 0..255
    const int lane = t & 63;
    const int wid  = t >> 6;              // 0..3
    const int wm   = wid >> 1;            // 0..1 (64-row band)
    const int wd   = wid & 1;             // 0..1 (32 d-cols, all 3 gates)
    const int crow = lane & 31;           // row/col within a 32-block
    const int hi   = lane >> 5;           // selects k-seg half

    // T1 XCD mapping: each XCD owns 8 consecutive f; d-tile innermost
    const int bid  = blockIdx.x;          // 0..8191
    const int xcd  = bid & 7;
    const int lid  = bid >> 3;
    const int work = xcd * 1024 + lid;
    const int f    = work >> 7;           // 0..63
    const int rem  = work & 127;
    const int mt   = rem >> 3;            // 0..15 (128-row tiles)
    const int dt   = rem & 7;             // 0..7
    const int n0   = mt * 128;
    const int d0   = dt * 64;

    const unsigned char* aSlab = xT + (long)((f * 16 + mt) * 8) * A_SLAB;
    const unsigned char* bSlab = wT + (long)((f * 8 + dt) * 8) * B_SLAB;
    const int ldsW = (t & 192) * 16;      // wid*1024 (wave-uniform)

    f32x16 acc[3][2];
#pragma unroll
    for (int g = 0; g < 3; ++g)
#pragma unroll
        for (int rb = 0; rb < 2; ++rb)
#pragma unroll
            for (int q = 0; q < 16; ++q)
                acc[g][rb][q] = 0.f;

    const int arow0 = wm * 64 + crow;          // rb=0 row
    const int arow1 = arow0 + 32;              // rb=1 row
    const int drow  = wd * 32 + crow;          // B row (d-col within gate)

    for (int kt = 0; kt < NKT; ++kt) {
        __syncthreads();   // prev iteration's ds_reads done
        // stage K-tile kt: identity 16B copies (k-major images)
#pragma unroll
        for (int p = 0; p < 4; ++p)
            gload16(aSlab + kt * A_SLAB + (p * 256 + t) * 16,
                    lds + p * 4096 + ldsW);
#pragma unroll
        for (int p = 0; p < 6; ++p)
            gload16(bSlab + kt * B_SLAB + (p * 256 + t) * 16,
                    lds + 16384 + p * 4096 + ldsW);
        __syncthreads();   // drains vmcnt -> tile visible

#pragma unroll
        for (int kk = 0; kk < 4; ++kk) {
            const int seg = 2 * kk + hi;       // 16B k-seg for this slice
            bf16x8 av[2], bv[3];
            {
                int off = seg * 2048 + arow0 * 16;   // contiguous across lanes
                av[0] = __builtin_bit_cast(bf16x8, *(const uint32x4*)(lds + off));
                off = seg * 2048 + arow1 * 16;
                av[1] = __builtin_bit_cast(bf16x8, *(const uint32x4*)(lds + off));
            }
#pragma unroll
            for (int g = 0; g < 3; ++g) {
                int off = 16384 + seg * 3072 + (g * 64 + drow) * 16;
                bv[g] = __builtin_bit_cast(bf16x8, *(const uint32x4*)(lds + off));
            }
            __builtin_amdgcn_s_setprio(1);
#pragma unroll
            for (int g = 0; g < 3; ++g)
#pragma unroll
                for (int rb = 0; rb < 2; ++rb)
                    acc[g][rb] = __builtin_amdgcn_mfma_f32_32x32x16_bf16(
                        av[rb], bv[g], acc[g][rb], 0, 0, 0);
            __builtin_amdgcn_s_setprio(0);
        }
    }

    // ---- fused gate epilogue: col = lane&31, row = (reg&3)+8*(reg>>2)+4*hi -
    const long bBase = (long)f * (3 * DD);
    const int d = d0 + wd * 32 + crow;
    const float bihr = b_ih[bBase + d];
    const float bihz = b_ih[bBase + DD + d];
    const float bihn = b_ih[bBase + 2 * DD + d];
    const float bhr  = b_hh[bBase + d];
    const float bhz  = b_hh[bBase + DD + d];
    const float bhn  = b_hh[bBase + 2 * DD + d];
#pragma unroll
    for (int rb = 0; rb < 2; ++rb) {
#pragma unroll
        for (int reg = 0; reg < 16; ++reg) {
            int row = wm * 64 + rb * 32 + (reg & 3) + 8 * (reg >> 2) + 4 * hi;
            float gr = acc[0][rb][reg] + bihr + bhr;
            float gz = acc[1][rb][reg] + bihz + bhz;
            float gy = acc[2][rb][reg] + bihn;
            float r  = fast_sigmoid(gr);
            float z  = fast_sigmoid(gz);
            float nv = fast_tanh(gy + r * bhn);
            long oi  = ((long)(n0 + row) * FF + f) * DD + d;
            out[oi]  = (1.0f - z) * nv;
        }
    }
}

// ---------------- fallback (R3 kernel) if ws too small ----------------
extern "C" __global__ __launch_bounds__(256, 3)
void gru_fused_fb(const float* __restrict__ x, const float* __restrict__ W,
                  const float* __restrict__ b_ih, const float* __restrict__ b_hh,
                  float* __restrict__ out)
{
    __shared__ __align__(16) unsigned char lds[28672];
    const int t     = threadIdx.x;
    const int lane  = t & 63;
    const int wid   = t >> 6;
    const int wm    = wid >> 1;
    const int wd    = wid & 1;
    const int lrow  = lane & 15;
    const int khalf = lane >> 4;
    const int bid  = blockIdx.x;
    const int xcd  = bid & 7;
    const int lid  = bid >> 3;
    const int work = xcd * 2048 + lid;
    const int f    = work >> 8;
    const int rem  = work & 255;
    const int n0   = (rem >> 4) * 128;
    const int d0   = (rem & 15) * 32;
    const int colSeg = t & 7;
    const int rBase  = t >> 3;
    const float* aPtr[4]; int aOff[4];
#pragma unroll
    for (int p = 0; p < 4; ++p) {
        int row = rBase + 32 * p;
        aPtr[p] = x + ((long)(n0 + row) * FF + f) * SS + colSeg * 8;
        aOff[p] = row * 128 + ((colSeg * 16) ^ ((row & 7) << 4));
    }
    const float* bPtr[3]; int bOff[3];
#pragma unroll
    for (int p = 0; p < 3; ++p) {
        int ra = rBase + 32 * p;
        int gate = ra >> 5, dr = ra & 31;
        bPtr[p] = W + ((long)f * 1536 + gate * DD + d0 + dr) * SS + colSeg * 8;
        bOff[p] = 16384 + gate * 4096 + dr * 128 + ((colSeg * 16) ^ ((dr & 7) << 4));
    }
    f32x4 acc[3][4];
#pragma unroll
    for (int g = 0; g < 3; ++g)
#pragma unroll
        for (int i = 0; i < 4; ++i) acc[g][i] = (f32x4){0.f, 0.f, 0.f, 0.f};
    f32x4 va[4][2], vb[3][2];
#pragma unroll
    for (int p = 0; p < 4; ++p) { const f32x4* g = (const f32x4*)aPtr[p]; va[p][0] = g[0]; va[p][1] = g[1]; }
#pragma unroll
    for (int p = 0; p < 3; ++p) { const f32x4* g = (const f32x4*)bPtr[p]; vb[p][0] = g[0]; vb[p][1] = g[1]; }
    for (int kt = 0; kt < 8; ++kt) {
        __syncthreads();
#pragma unroll
        for (int p = 0; p < 4; ++p) *(ushort8*)(lds + aOff[p]) = cvt8(va[p][0], va[p][1]);
#pragma unroll
        for (int p = 0; p < 3; ++p) *(ushort8*)(lds + bOff[p]) = cvt8(vb[p][0], vb[p][1]);
        __syncthreads();
        if (kt + 1 < 8) {
            const long koff = (long)(kt + 1) * 64;
#pragma unroll
            for (int p = 0; p < 4; ++p) { const f32x4* g = (const f32x4*)(aPtr[p] + koff); va[p][0] = g[0]; va[p][1] = g[1]; }
#pragma unroll
            for (int p = 0; p < 3; ++p) { const f32x4* g = (const f32x4*)(bPtr[p] + koff); vb[p][0] = g[0]; vb[p][1] = g[1]; }
        }
#pragma unroll
        for (int kb = 0; kb < 2; ++kb) {
            bf16x8 af[4];
#pragma unroll
            for (int i = 0; i < 4; ++i) {
                int row = wm * 64 + i * 16 + lrow;
                int off = row * 128 + ((kb * 64 + khalf * 16) ^ ((row & 7) << 4));
                af[i] = __builtin_bit_cast(bf16x8, *(const uint32x4*)(lds + off));
            }
            bf16x8 bfr[3];
#pragma unroll
            for (int g = 0; g < 3; ++g) {
                int dr = wd * 16 + lrow;
                int off = 16384 + g * 4096 + dr * 128 + ((kb * 64 + khalf * 16) ^ ((dr & 7) << 4));
                bfr[g] = __builtin_bit_cast(bf16x8, *(const uint32x4*)(lds + off));
            }
#pragma unroll
            for (int g = 0; g < 3; ++g)
#pragma unroll
                for (int i = 0; i < 4; ++i)
                    acc[g][i] = __builtin_amdgcn_mfma_f32_16x16x32_bf16(af[i], bfr[g], acc[g][i], 0, 0, 0);
        }
    }
    const long bBase = (long)f * 1536;
    {
        int d = d0 + wd * 16 + lrow;
        float bihr = b_ih[bBase + d], bihz = b_ih[bBase + DD + d], bihn = b_ih[bBase + 2 * DD + d];
        float bhr = b_hh[bBase + d], bhz = b_hh[bBase + DD + d], bhn = b_hh[bBase + 2 * DD + d];
#pragma unroll
    for (int i = 0; i < 4; ++i)
#pragma unroll
            for (int q = 0; q < 4; ++q) {
                int row = wm * 64 + i * 16 + khalf * 4 + q;
                float r  = fast_sigmoid(acc[0][i][q] + bihr + bhr);
                float z  = fast_sigmoid(acc[1][i][q] + bihz + bhz);
                float nv = fast_tanh(acc[2][i][q] + bihn + r * bhn);
                out[((long)(n0 + row) * FF + f) * DD + d] = (1.0f - z) * nv;
            }
    }
}

extern "C" void kernel_launch(void* const* d_in, const int* in_sizes, int n_in,
                              void* d_out, int out_size, void* d_ws, size_t ws_size,
                              hipStream_t stream) {
    const float* x   = (const float*)d_in[0];
    const float* W   = (const float*)d_in[1];
    const float* bih = (const float*)d_in[2];
    const float* bhh = (const float*)d_in[3];
    float* out       = (float*)d_out;

    if (ws_size >= (size_t)(XT_BYTES + WT_BYTES)) {
        unsigned char* xT = (unsigned char*)d_ws;
        unsigned char* wT = xT + XT_BYTES;
        prep_xw<<<dim3(12288), dim3(256), 0, stream>>>(x, W, (ushort8*)xT, (ushort8*)wT);
        gru_gemm<<<dim3(8192), dim3(256), 0, stream>>>(xT, wT, bih, bhh, out);
    } else {
        gru_fused_fb<<<dim3(16384), dim3(256), 0, stream>>>(x, W, bih, bhh, out);
    }
}